// Round 11
// baseline (4643.832 us; speedup 1.0000x reference)
//
#include <hip/hip_runtime.h>
#include <math.h>

#define N_TOTAL   32768
#define K_ENT     4096
#define DIM       64
#define BM        64
#define BK        128
#define CAPG      16
#define EPS       1.0f

typedef __attribute__((ext_vector_type(4))) float f32x4;
typedef __attribute__((ext_vector_type(8))) short bf16x8;
typedef __attribute__((ext_vector_type(4))) unsigned short u16x4;

// ws layout (float offsets) — total ~2.8 MB
#define WS_NCB    0            // 4096 floats: -0.5*||w_k||^2
#define WS_WHI    4096         // 4096x64 ushort hi-plane (512 KB)
#define WS_CNT    135168       // 32768 ints: per-row candidate count
#define WS_CAND   167936       // 32768 x CAPG ints: candidate lists (2 MB)
// out layout (fp32 element offsets)
#define OUT_ZQ    0
#define OUT_IDX   2097152
#define OUT_LOSS  2129920
#define OUT_ENC   2134016
#define OUT_EMB   2138112

#define NEG_BIG   -3.0e38f

__device__ __forceinline__ float bf2f(unsigned short u) {
  return __uint_as_float(((unsigned int)u) << 16);
}
__device__ __forceinline__ unsigned short f2bf(float f) {  // RNE
  unsigned int b = __float_as_uint(f);
  return (unsigned short)((b + 0x7fffu + ((b >> 16) & 1u)) >> 16);
}

// fused: bf16 hi-plane split + ncb = -0.5*||w_k||^2 (16-lane shfl reduce)
__global__ __launch_bounds__(256) void prep_kernel(
    const float* __restrict__ w, unsigned short* __restrict__ whi,
    float* __restrict__ ncb) {
  int i = blockIdx.x * 256 + threadIdx.x;      // float4 unit, 0..65535
  float4 v = ((const float4*)w)[i];
  u16x4 h;
  h[0] = f2bf(v.x); h[1] = f2bf(v.y); h[2] = f2bf(v.z); h[3] = f2bf(v.w);
  ((u16x4*)whi)[i] = h;
  float s = fmaf(v.x, v.x, fmaf(v.y, v.y, fmaf(v.z, v.z, v.w * v.w)));
  s += __shfl_xor(s, 1); s += __shfl_xor(s, 2);
  s += __shfl_xor(s, 4); s += __shfl_xor(s, 8);
  if ((threadIdx.x & 15) == 0) ncb[i >> 4] = -0.5f * s;
}

// Single-pass MFMA argmax-collect. Grid 1024: block = 64 rows x half of K
// (K-split 2), staggered chunk order to spread L2 traffic. Operands swapped
// (A = w entries, B = z rows) so D-row = entry: a row's 8 in-thread entries
// reduce with fmax; full 32-entry chunk row-max needs only shfl_xor(16,32).
// Candidates (score >= runningRowMax - EPS) go to global per-row lists —
// superset of {true argmax} for ANY visit order since running max only grows.
// NO LDS, NO barriers. Exactness restored later by fp64 rescore.
__global__ __launch_bounds__(256, 3) void argmax_kernel(
    const float* __restrict__ z, const unsigned short* __restrict__ whi,
    const float* __restrict__ ncb, int* __restrict__ cnt,
    int* __restrict__ cand) {
  const int tid = threadIdx.x;
  const int n0  = (blockIdx.x >> 1) * BM;
  const int khalf = blockIdx.x & 1;
  const int st  = blockIdx.x & 15;     // stagger
  const int wv  = tid >> 6;            // wave 0..3
  const int ln  = tid & 63;
  const int g   = ln >> 4;             // k-group 0..3
  const int lm  = ln & 15;
  const int estripe = wv * 32;         // wave's entry stripe within chunk

  // ---- B fragments: z rows rt*16+lm, k = s*32+g*8 (hoisted, registers) ----
  bf16x8 bz[4][2];
  #pragma unroll
  for (int rt = 0; rt < 4; ++rt) {
    const float* zr = z + (size_t)(n0 + rt * 16 + lm) * DIM;
    #pragma unroll
    for (int s = 0; s < 2; ++s) {
      float4 f0 = *(const float4*)(zr + s * 32 + g * 8);
      float4 f1 = *(const float4*)(zr + s * 32 + g * 8 + 4);
      float ff[8] = {f0.x, f0.y, f0.z, f0.w, f1.x, f1.y, f1.z, f1.w};
      bf16x8 h;
      #pragma unroll
      for (int i = 0; i < 8; ++i) h[i] = (short)f2bf(ff[i]);
      bz[rt][s] = h;
    }
  }

  float m[4];
  #pragma unroll
  for (int i = 0; i < 4; ++i) m[i] = NEG_BIG;

  bf16x8 awA[2][2], awB[2][2];
  float4 ncA[2], ncB[2];

  auto chunkbase = [&](int i) {
    return (khalf * 16 + ((i + st) & 15)) * BK;
  };
  auto loadW = [&](int kcb, bf16x8 (&aw)[2][2], float4 (&nc)[2]) {
    #pragma unroll
    for (int et = 0; et < 2; ++et) {
      const int ebase = kcb + estripe + et * 16;
      nc[et] = *(const float4*)(ncb + ebase + g * 4);
      const unsigned short* wr = whi + (size_t)(ebase + lm) * DIM + g * 8;
      aw[et][0] = *(const bf16x8*)(wr);
      aw[et][1] = *(const bf16x8*)(wr + 32);
    }
  };
  auto comp = [&](int kcb, const bf16x8 (&aw)[2][2], const float4 (&nc)[2]) {
    f32x4 acc[2][4];
    #pragma unroll
    for (int et = 0; et < 2; ++et)
      #pragma unroll
      for (int rt = 0; rt < 4; ++rt)
        acc[et][rt] = (f32x4){nc[et].x, nc[et].y, nc[et].z, nc[et].w};
    #pragma unroll
    for (int et = 0; et < 2; ++et)
      #pragma unroll
      for (int s = 0; s < 2; ++s)
        #pragma unroll
        for (int rt = 0; rt < 4; ++rt)
          acc[et][rt] = __builtin_amdgcn_mfma_f32_16x16x32_bf16(
              aw[et][s], bz[rt][s], acc[et][rt], 0, 0, 0);
    #pragma unroll
    for (int rt = 0; rt < 4; ++rt) {
      float cm = fmaxf(
          fmaxf(fmaxf(acc[0][rt][0], acc[0][rt][1]),
                fmaxf(acc[0][rt][2], acc[0][rt][3])),
          fmaxf(fmaxf(acc[1][rt][0], acc[1][rt][1]),
                fmaxf(acc[1][rt][2], acc[1][rt][3])));
      cm = fmaxf(cm, __shfl_xor(cm, 16));
      cm = fmaxf(cm, __shfl_xor(cm, 32));
      float nm = fmaxf(m[rt], cm);
      m[rt] = nm;
      const float thr = nm - EPS;
      const int rown = n0 + rt * 16 + lm;
      #pragma unroll
      for (int et = 0; et < 2; ++et)
        #pragma unroll
        for (int j = 0; j < 4; ++j) {
          if (__builtin_expect(acc[et][rt][j] >= thr, 0)) {
            int e = kcb + estripe + et * 16 + g * 4 + j;
            int p = atomicAdd(&cnt[rown], 1);
            if (p < CAPG) cand[rown * CAPG + p] = e;
          }
        }
    }
  };

  loadW(chunkbase(0), awA, ncA);
  for (int i = 0; i < 16; i += 2) {
    loadW(chunkbase(i + 1), awB, ncB);
    comp(chunkbase(i), awA, ncA);
    if (i + 2 < 16) loadW(chunkbase(i + 2), awA, ncA);
    comp(chunkbase(i + 1), awB, ncB);
  }
}

// Fused exact-rescore + gather. Block = 1 (b,s): 8 waves, one row each;
// 64 lanes d-parallel. fp64 candidate rescore via shfl_xor butterfly
// (order-independent -> replay-deterministic); lowest-index tie-break.
// cnt>CAPG (never expected): deterministic lane-serial full rescan.
__global__ __launch_bounds__(512) void rescore_gather_kernel(
    const float* __restrict__ z, const float* __restrict__ w,
    const int* __restrict__ cnt, const int* __restrict__ cand,
    float* __restrict__ out_idx, float* __restrict__ out_zq,
    float* __restrict__ out_loss, float* __restrict__ enc,
    float* __restrict__ emb) {
  const int bs = blockIdx.x;
  const int tid = threadIdx.x;
  const int h = tid >> 6, d = tid & 63;
  const int n = bs * 8 + h;
  const float zf = z[(size_t)n * DIM + d];
  const double zv = (double)zf;

  int nn = cnt[n];
  double best = -1.0e300;
  int win = 0;
  if (nn <= CAPG) {
    for (int p = 0; p < nn; ++p) {
      int c = cand[n * CAPG + p];
      double wv = (double)w[(size_t)c * DIM + d];
      double td = zv * wv, ud = wv * wv;
      #pragma unroll
      for (int mk = 32; mk >= 1; mk >>= 1) {
        td += __shfl_xor(td, mk);
        ud += __shfl_xor(ud, mk);
      }
      double sd = 2.0 * td - ud;
      if (sd > best || (sd == best && c < win)) { best = sd; win = c; }
    }
  } else {                             // overflow fallback: full exact scan
    double bl = -1.0e300;
    int wl = 0;
    for (int t = 0; t < 64; ++t) {
      int c = t * 64 + d;
      double td = 0.0, ud = 0.0;
      for (int d2 = 0; d2 < DIM; ++d2) {
        double wv = (double)w[(size_t)c * DIM + d2];
        double z2 = (double)z[(size_t)n * DIM + d2];
        td = fma(z2, wv, td);
        ud = fma(wv, wv, ud);
      }
      double sd = 2.0 * td - ud;
      if (sd > bl || (sd == bl && c < wl)) { bl = sd; wl = c; }
    }
    #pragma unroll
    for (int mk = 1; mk <= 32; mk <<= 1) {
      double os = __shfl_xor(bl, mk);
      int   oi = __shfl_xor(wl, mk);
      if (os > bl || (os == bl && oi < wl)) { bl = os; wl = oi; }
    }
    win = wl;
  }

  int k = win;
  k = (k < 0) ? 0 : ((k > K_ENT - 1) ? (K_ENT - 1) : k);  // safety clamp
  if (d == 0) out_idx[n] = (float)k;

  float wvf = w[(size_t)k * DIM + d];
  float stv = zf + (wvf - zf);              // straight-through, ref fp order
  out_zq[(size_t)n * DIM + d] = stv;
  float diff = zf - wvf;
  float s = diff * diff;
  #pragma unroll
  for (int mm = 32; mm >= 1; mm >>= 1) s += __shfl_down(s, mm, 64);
  __shared__ float red[8];
  if ((tid & 63) == 0) red[tid >> 6] = s;
  __syncthreads();
  if (tid == 0) {
    float t = 0.f;
    #pragma unroll
    for (int i = 0; i < 8; ++i) t += red[i];
    out_loss[bs] = t * (1.0f / 512.0f);
  }
  atomicAdd(&emb[(size_t)k * DIM + d], zf);
  if (d == 0) atomicAdd(&enc[k], 1.0f);
}

extern "C" void kernel_launch(void* const* d_in, const int* in_sizes, int n_in,
                              void* d_out, int out_size, void* d_ws, size_t ws_size,
                              hipStream_t stream) {
  const float* z = (const float*)d_in[0];
  const float* w = (const float*)d_in[1];
  float* ws  = (float*)d_ws;
  float* ncb = ws + WS_NCB;
  unsigned short* whi = (unsigned short*)(ws + WS_WHI);
  int* cnt  = (int*)(ws + WS_CNT);
  int* cand = (int*)(ws + WS_CAND);
  float* out = (float*)d_out;

  // zero scatter accumulators (enc+emb, 1 MB) and candidate counters (128 KB)
  hipMemsetAsync(out + OUT_ENC, 0, (size_t)(4096 + 262144) * sizeof(float),
                 stream);
  hipMemsetAsync(cnt, 0, (size_t)N_TOTAL * sizeof(int), stream);

  prep_kernel<<<(K_ENT * DIM / 4) / 256, 256, 0, stream>>>(w, whi, ncb);
  argmax_kernel<<<(N_TOTAL / BM) * 2, 256, 0, stream>>>(z, whi, ncb, cnt,
                                                        cand);
  rescore_gather_kernel<<<N_TOTAL / 8, 512, 0, stream>>>(
      z, w, cnt, cand, out + OUT_IDX, out + OUT_ZQ, out + OUT_LOSS,
      out + OUT_ENC, out + OUT_EMB);
}

// Round 12
// 151.477 us; speedup vs baseline: 30.6571x; 30.6571x over previous
//
#include <hip/hip_runtime.h>
#include <math.h>

#define N_TOTAL   32768
#define K_ENT     4096
#define DIM       64
#define BM        64
#define BK        128
#define CAPG      16
#define EPS       1.0f
#define BIAS      256.0f

typedef __attribute__((ext_vector_type(4))) float f32x4;
typedef __attribute__((ext_vector_type(8))) short bf16x8;
typedef __attribute__((ext_vector_type(4))) unsigned short u16x4;

// ws layout (float offsets) — total ~2.9 MB
#define WS_NCB    0            // 4096 floats: BIAS - 0.5*||w_k||^2
#define WS_WHI    4096         // 4096x64 ushort hi-plane (512 KB)
#define WS_RMX    135168       // 32768 uints: per-row biased max (as uint)
#define WS_CNT    167936       // 32768 ints: per-row candidate count
#define WS_CAND   200704       // 32768 x CAPG ints: candidate lists (2 MB)
// out layout (fp32 element offsets)
#define OUT_ZQ    0
#define OUT_IDX   2097152
#define OUT_LOSS  2129920
#define OUT_ENC   2134016
#define OUT_EMB   2138112

#define NEG_BIG   -3.0e38f

__device__ __forceinline__ float bf2f(unsigned short u) {
  return __uint_as_float(((unsigned int)u) << 16);
}
__device__ __forceinline__ unsigned short f2bf(float f) {  // RNE
  unsigned int b = __float_as_uint(f);
  return (unsigned short)((b + 0x7fffu + ((b >> 16) & 1u)) >> 16);
}

// fused: bf16 hi-plane split + ncb = BIAS - 0.5*||w_k||^2
__global__ __launch_bounds__(256) void prep_kernel(
    const float* __restrict__ w, unsigned short* __restrict__ whi,
    float* __restrict__ ncb) {
  int i = blockIdx.x * 256 + threadIdx.x;      // float4 unit, 0..65535
  float4 v = ((const float4*)w)[i];
  u16x4 h;
  h[0] = f2bf(v.x); h[1] = f2bf(v.y); h[2] = f2bf(v.z); h[3] = f2bf(v.w);
  ((u16x4*)whi)[i] = h;
  float s = fmaf(v.x, v.x, fmaf(v.y, v.y, fmaf(v.z, v.z, v.w * v.w)));
  s += __shfl_xor(s, 1); s += __shfl_xor(s, 2);
  s += __shfl_xor(s, 4); s += __shfl_xor(s, 8);
  if ((threadIdx.x & 15) == 0) ncb[i >> 4] = BIAS - 0.5f * s;
}

// Phase 1: per-row biased max. Grid 1024 (K-split 2, staggered chunk order).
// Swapped operands (A=w, B=z): D-row = entry, D-col = z-row. Rolled chunk
// loop (tiny body -> I$-resident), dbuf register prefetch, NO LDS/barriers.
// Epilogue: fmax chains only; final cross-lane shfl merge + global atomicMax
// on float-as-uint (scores biased positive -> uint order == float order).
__global__ __launch_bounds__(256, 3) void maxes_kernel(
    const float* __restrict__ z, const unsigned short* __restrict__ whi,
    const float* __restrict__ ncb, unsigned int* __restrict__ rmx) {
  const int tid = threadIdx.x;
  const int n0  = (blockIdx.x >> 1) * BM;
  const int khalf = blockIdx.x & 1;
  const int st  = blockIdx.x & 15;
  const int wv  = tid >> 6;
  const int ln  = tid & 63;
  const int g   = ln >> 4;
  const int lm  = ln & 15;
  const int estripe = wv * 32;

  bf16x8 bz[4][2];
  #pragma unroll
  for (int rt = 0; rt < 4; ++rt) {
    const float* zr = z + (size_t)(n0 + rt * 16 + lm) * DIM;
    #pragma unroll
    for (int s = 0; s < 2; ++s) {
      float4 f0 = *(const float4*)(zr + s * 32 + g * 8);
      float4 f1 = *(const float4*)(zr + s * 32 + g * 8 + 4);
      float ff[8] = {f0.x, f0.y, f0.z, f0.w, f1.x, f1.y, f1.z, f1.w};
      bf16x8 h;
      #pragma unroll
      for (int i = 0; i < 8; ++i) h[i] = (short)f2bf(ff[i]);
      bz[rt][s] = h;
    }
  }

  float m[4];
  #pragma unroll
  for (int i = 0; i < 4; ++i) m[i] = NEG_BIG;

  bf16x8 awA[2][2], awB[2][2];
  float4 ncA[2], ncB[2];

  auto chunkbase = [&](int i) { return (khalf * 16 + ((i + st) & 15)) * BK; };
  auto loadW = [&](int kcb, bf16x8 (&aw)[2][2], float4 (&nc)[2]) {
    #pragma unroll
    for (int et = 0; et < 2; ++et) {
      const int ebase = kcb + estripe + et * 16;
      nc[et] = *(const float4*)(ncb + ebase + g * 4);
      const unsigned short* wr = whi + (size_t)(ebase + lm) * DIM + g * 8;
      aw[et][0] = *(const bf16x8*)(wr);
      aw[et][1] = *(const bf16x8*)(wr + 32);
    }
  };
  auto comp = [&](const bf16x8 (&aw)[2][2], const float4 (&nc)[2]) {
    f32x4 acc[2][4];
    #pragma unroll
    for (int et = 0; et < 2; ++et)
      #pragma unroll
      for (int rt = 0; rt < 4; ++rt)
        acc[et][rt] = (f32x4){nc[et].x, nc[et].y, nc[et].z, nc[et].w};
    #pragma unroll
    for (int et = 0; et < 2; ++et)
      #pragma unroll
      for (int s = 0; s < 2; ++s)
        #pragma unroll
        for (int rt = 0; rt < 4; ++rt)
          acc[et][rt] = __builtin_amdgcn_mfma_f32_16x16x32_bf16(
              aw[et][s], bz[rt][s], acc[et][rt], 0, 0, 0);
    #pragma unroll
    for (int rt = 0; rt < 4; ++rt) {
      float cm = fmaxf(
          fmaxf(fmaxf(acc[0][rt][0], acc[0][rt][1]),
                fmaxf(acc[0][rt][2], acc[0][rt][3])),
          fmaxf(fmaxf(acc[1][rt][0], acc[1][rt][1]),
                fmaxf(acc[1][rt][2], acc[1][rt][3])));
      m[rt] = fmaxf(m[rt], cm);
    }
  };

  loadW(chunkbase(0), awA, ncA);
  #pragma unroll 1
  for (int i = 0; i < 16; i += 2) {
    loadW(chunkbase(i + 1), awB, ncB);
    comp(awA, ncA);
    if (i + 2 < 16) loadW(chunkbase(i + 2), awA, ncA);
    comp(awB, ncB);
  }

  #pragma unroll
  for (int rt = 0; rt < 4; ++rt) {
    m[rt] = fmaxf(m[rt], __shfl_xor(m[rt], 16));
    m[rt] = fmaxf(m[rt], __shfl_xor(m[rt], 32));
  }
  if (ln < 16) {
    #pragma unroll
    for (int rt = 0; rt < 4; ++rt)
      atomicMax(&rmx[n0 + rt * 16 + ln], __float_as_uint(m[rt]));
  }
}

// Phase 2: identical sweep (bit-identical scores), collect entries with
// score >= rowmax - EPS into global per-row lists. One branch per rt per
// chunk via fmax-hit test (taken ~1 in 100).
__global__ __launch_bounds__(256, 3) void collect_kernel(
    const float* __restrict__ z, const unsigned short* __restrict__ whi,
    const float* __restrict__ ncb, const unsigned int* __restrict__ rmx,
    int* __restrict__ cnt, int* __restrict__ cand) {
  const int tid = threadIdx.x;
  const int n0  = (blockIdx.x >> 1) * BM;
  const int khalf = blockIdx.x & 1;
  const int st  = blockIdx.x & 15;
  const int wv  = tid >> 6;
  const int ln  = tid & 63;
  const int g   = ln >> 4;
  const int lm  = ln & 15;
  const int estripe = wv * 32;

  bf16x8 bz[4][2];
  #pragma unroll
  for (int rt = 0; rt < 4; ++rt) {
    const float* zr = z + (size_t)(n0 + rt * 16 + lm) * DIM;
    #pragma unroll
    for (int s = 0; s < 2; ++s) {
      float4 f0 = *(const float4*)(zr + s * 32 + g * 8);
      float4 f1 = *(const float4*)(zr + s * 32 + g * 8 + 4);
      float ff[8] = {f0.x, f0.y, f0.z, f0.w, f1.x, f1.y, f1.z, f1.w};
      bf16x8 h;
      #pragma unroll
      for (int i = 0; i < 8; ++i) h[i] = (short)f2bf(ff[i]);
      bz[rt][s] = h;
    }
  }

  float thr[4];
  #pragma unroll
  for (int rt = 0; rt < 4; ++rt)
    thr[rt] = __uint_as_float(rmx[n0 + rt * 16 + lm]) - EPS;

  bf16x8 awA[2][2], awB[2][2];
  float4 ncA[2], ncB[2];

  auto chunkbase = [&](int i) { return (khalf * 16 + ((i + st) & 15)) * BK; };
  auto loadW = [&](int kcb, bf16x8 (&aw)[2][2], float4 (&nc)[2]) {
    #pragma unroll
    for (int et = 0; et < 2; ++et) {
      const int ebase = kcb + estripe + et * 16;
      nc[et] = *(const float4*)(ncb + ebase + g * 4);
      const unsigned short* wr = whi + (size_t)(ebase + lm) * DIM + g * 8;
      aw[et][0] = *(const bf16x8*)(wr);
      aw[et][1] = *(const bf16x8*)(wr + 32);
    }
  };
  auto comp = [&](int kcb, const bf16x8 (&aw)[2][2], const float4 (&nc)[2]) {
    f32x4 acc[2][4];
    #pragma unroll
    for (int et = 0; et < 2; ++et)
      #pragma unroll
      for (int rt = 0; rt < 4; ++rt)
        acc[et][rt] = (f32x4){nc[et].x, nc[et].y, nc[et].z, nc[et].w};
    #pragma unroll
    for (int et = 0; et < 2; ++et)
      #pragma unroll
      for (int s = 0; s < 2; ++s)
        #pragma unroll
        for (int rt = 0; rt < 4; ++rt)
          acc[et][rt] = __builtin_amdgcn_mfma_f32_16x16x32_bf16(
              aw[et][s], bz[rt][s], acc[et][rt], 0, 0, 0);
    #pragma unroll
    for (int rt = 0; rt < 4; ++rt) {
      float hm = fmaxf(
          fmaxf(fmaxf(acc[0][rt][0], acc[0][rt][1]),
                fmaxf(acc[0][rt][2], acc[0][rt][3])),
          fmaxf(fmaxf(acc[1][rt][0], acc[1][rt][1]),
                fmaxf(acc[1][rt][2], acc[1][rt][3])));
      if (__builtin_expect(hm >= thr[rt], 0)) {   // rare
        const int rown = n0 + rt * 16 + lm;
        #pragma unroll
        for (int et = 0; et < 2; ++et)
          #pragma unroll
          for (int j = 0; j < 4; ++j) {
            if (acc[et][rt][j] >= thr[rt]) {
              int e = kcb + estripe + et * 16 + g * 4 + j;
              int p = atomicAdd(&cnt[rown], 1);
              if (p < CAPG) cand[rown * CAPG + p] = e;
            }
          }
      }
    }
  };

  loadW(chunkbase(0), awA, ncA);
  #pragma unroll 1
  for (int i = 0; i < 16; i += 2) {
    loadW(chunkbase(i + 1), awB, ncB);
    comp(chunkbase(i), awA, ncA);
    if (i + 2 < 16) loadW(chunkbase(i + 2), awA, ncA);
    comp(chunkbase(i + 1), awB, ncB);
  }
}

// Exact fp64 rescore (lane-per-candidate) + gather/loss/scatter.
// Block = 1 (b,s): 8 waves, one row each.
__global__ __launch_bounds__(512) void rescore_gather_kernel(
    const float* __restrict__ z, const float* __restrict__ w,
    const int* __restrict__ cnt, const int* __restrict__ cand,
    float* __restrict__ out_idx, float* __restrict__ out_zq,
    float* __restrict__ out_loss, float* __restrict__ enc,
    float* __restrict__ emb) {
  const int bs = blockIdx.x;
  const int tid = threadIdx.x;
  const int h = tid >> 6, d = tid & 63;
  const int n = bs * 8 + h;

  int nn = cnt[n];
  double bl = -1.0e300;
  int wl = 0x7fffffff;
  if (nn <= CAPG) {
    if (d < nn) {                       // lane d rescores candidate d
      int c = cand[n * CAPG + d];
      double td = 0.0, ud = 0.0;
      #pragma unroll 8
      for (int d2 = 0; d2 < DIM; ++d2) {
        double wv = (double)w[(size_t)c * DIM + d2];
        double zv = (double)z[(size_t)n * DIM + d2];
        td = fma(zv, wv, td);
        ud = fma(wv, wv, ud);
      }
      bl = 2.0 * td - ud;
      wl = c;
    }
  } else {                              // overflow: full exact scan (P~0)
    for (int t = 0; t < 64; ++t) {
      int c = t * 64 + d;
      double td = 0.0, ud = 0.0;
      for (int d2 = 0; d2 < DIM; ++d2) {
        double wv = (double)w[(size_t)c * DIM + d2];
        double zv = (double)z[(size_t)n * DIM + d2];
        td = fma(zv, wv, td);
        ud = fma(wv, wv, ud);
      }
      double sd = 2.0 * td - ud;
      if (sd > bl || (sd == bl && c < wl)) { bl = sd; wl = c; }
    }
  }
  #pragma unroll
  for (int mk = 1; mk <= 32; mk <<= 1) {
    double os = __shfl_xor(bl, mk);
    int   oi = __shfl_xor(wl, mk);
    if (os > bl || (os == bl && oi < wl)) { bl = os; wl = oi; }
  }
  int k = wl;
  k = (k < 0) ? 0 : ((k > K_ENT - 1) ? (K_ENT - 1) : k);  // safety clamp
  if (d == 0) out_idx[n] = (float)k;

  const float zf = z[(size_t)n * DIM + d];
  float wvf = w[(size_t)k * DIM + d];
  float stv = zf + (wvf - zf);              // straight-through, ref fp order
  out_zq[(size_t)n * DIM + d] = stv;
  float diff = zf - wvf;
  float s = diff * diff;
  #pragma unroll
  for (int mm = 32; mm >= 1; mm >>= 1) s += __shfl_down(s, mm, 64);
  __shared__ float red[8];
  if ((tid & 63) == 0) red[tid >> 6] = s;
  __syncthreads();
  if (tid == 0) {
    float t = 0.f;
    #pragma unroll
    for (int i = 0; i < 8; ++i) t += red[i];
    out_loss[bs] = t * (1.0f / 512.0f);
  }
  atomicAdd(&emb[(size_t)k * DIM + d], zf);
  if (d == 0) atomicAdd(&enc[k], 1.0f);
}

extern "C" void kernel_launch(void* const* d_in, const int* in_sizes, int n_in,
                              void* d_out, int out_size, void* d_ws, size_t ws_size,
                              hipStream_t stream) {
  const float* z = (const float*)d_in[0];
  const float* w = (const float*)d_in[1];
  float* ws  = (float*)d_ws;
  float* ncb = ws + WS_NCB;
  unsigned short* whi = (unsigned short*)(ws + WS_WHI);
  unsigned int* rmx = (unsigned int*)(ws + WS_RMX);
  int* cnt  = (int*)(ws + WS_CNT);
  int* cand = (int*)(ws + WS_CAND);
  float* out = (float*)d_out;

  // zero scatter accumulators (1 MB) and rowmax+cnt (256 KB, contiguous)
  hipMemsetAsync(out + OUT_ENC, 0, (size_t)(4096 + 262144) * sizeof(float),
                 stream);
  hipMemsetAsync(rmx, 0, (size_t)(2 * N_TOTAL) * sizeof(int), stream);

  prep_kernel<<<(K_ENT * DIM / 4) / 256, 256, 0, stream>>>(w, whi, ncb);
  maxes_kernel<<<(N_TOTAL / BM) * 2, 256, 0, stream>>>(z, whi, ncb, rmx);
  collect_kernel<<<(N_TOTAL / BM) * 2, 256, 0, stream>>>(z, whi, ncb, rmx,
                                                         cnt, cand);
  rescore_gather_kernel<<<N_TOTAL / 8, 512, 0, stream>>>(
      z, w, cnt, cand, out + OUT_IDX, out + OUT_ZQ, out + OUT_LOSS,
      out + OUT_ENC, out + OUT_EMB);
}

// Round 13
// 126.032 us; speedup vs baseline: 36.8466x; 1.2019x over previous
//
#include <hip/hip_runtime.h>
#include <math.h>

#define N_TOTAL   32768
#define K_ENT     4096
#define DIM       64
#define BMR       128
#define BK        128
#define CAPG      16
#define EPS       1.0f
#define BIAS      256.0f

typedef __attribute__((ext_vector_type(4))) float f32x4;
typedef __attribute__((ext_vector_type(8))) short bf16x8;
typedef __attribute__((ext_vector_type(4))) unsigned short u16x4;

// ws layout (float offsets) — total ~2.9 MB
#define WS_NCB    0            // 4096 floats: BIAS - 0.5*||w_k||^2
#define WS_WHI    4096         // 4096x64 ushort hi-plane (512 KB)
#define WS_RMX    135168       // 32768 uints: per-row biased max (as uint)
#define WS_CNT    167936       // 32768 ints: per-row candidate count
#define WS_CAND   200704       // 32768 x CAPG ints: candidate lists (2 MB)
// out layout (fp32 element offsets)
#define OUT_ZQ    0
#define OUT_IDX   2097152
#define OUT_LOSS  2129920
#define OUT_ENC   2134016
#define OUT_EMB   2138112

#define NEG_BIG   -3.0e38f

__device__ __forceinline__ float bf2f(unsigned short u) {
  return __uint_as_float(((unsigned int)u) << 16);
}
__device__ __forceinline__ unsigned short f2bf(float f) {  // RNE
  unsigned int b = __float_as_uint(f);
  return (unsigned short)((b + 0x7fffu + ((b >> 16) & 1u)) >> 16);
}

// fused: bf16 hi-plane split + ncb = BIAS - 0.5*||w_k||^2
__global__ __launch_bounds__(256) void prep_kernel(
    const float* __restrict__ w, unsigned short* __restrict__ whi,
    float* __restrict__ ncb) {
  int i = blockIdx.x * 256 + threadIdx.x;      // float4 unit, 0..65535
  float4 v = ((const float4*)w)[i];
  u16x4 h;
  h[0] = f2bf(v.x); h[1] = f2bf(v.y); h[2] = f2bf(v.z); h[3] = f2bf(v.w);
  ((u16x4*)whi)[i] = h;
  float s = fmaf(v.x, v.x, fmaf(v.y, v.y, fmaf(v.z, v.z, v.w * v.w)));
  s += __shfl_xor(s, 1); s += __shfl_xor(s, 2);
  s += __shfl_xor(s, 4); s += __shfl_xor(s, 8);
  if ((threadIdx.x & 15) == 0) ncb[i >> 4] = BIAS - 0.5f * s;
}

// Phase 1: per-row biased max. Block = 128 rows x half of K (grid 512,
// staggered chunk order). Swapped operands (A=w, B=z): per chunk each wave
// issues 32 MFMAs (~310 cyc) against 4x16B whi loads — AI doubled vs r12 so
// the compute phase itself covers loaded-L2 latency. 2-deep named prefetch,
// NO LDS/barriers. Epilogue: fmax chains; shfl merge; global atomicMax on
// float-as-uint (biased-positive scores: uint order == float order).
__global__ __launch_bounds__(256, 2) void maxes_kernel(
    const float* __restrict__ z, const unsigned short* __restrict__ whi,
    const float* __restrict__ ncb, unsigned int* __restrict__ rmx) {
  const int tid = threadIdx.x;
  const int n0  = (blockIdx.x >> 1) * BMR;
  const int khalf = blockIdx.x & 1;
  const int st  = blockIdx.x & 15;
  const int wv  = tid >> 6;
  const int ln  = tid & 63;
  const int g   = ln >> 4;
  const int lm  = ln & 15;
  const int estripe = wv * 32;

  bf16x8 bz[8][2];
  #pragma unroll
  for (int rt = 0; rt < 8; ++rt) {
    const float* zr = z + (size_t)(n0 + rt * 16 + lm) * DIM;
    #pragma unroll
    for (int s = 0; s < 2; ++s) {
      float4 f0 = *(const float4*)(zr + s * 32 + g * 8);
      float4 f1 = *(const float4*)(zr + s * 32 + g * 8 + 4);
      float ff[8] = {f0.x, f0.y, f0.z, f0.w, f1.x, f1.y, f1.z, f1.w};
      bf16x8 h;
      #pragma unroll
      for (int i = 0; i < 8; ++i) h[i] = (short)f2bf(ff[i]);
      bz[rt][s] = h;
    }
  }

  float m[8];
  #pragma unroll
  for (int i = 0; i < 8; ++i) m[i] = NEG_BIG;

  bf16x8 awA[2][2], awB[2][2];
  float4 ncA[2], ncB[2];

  auto chunkbase = [&](int i) { return (khalf * 16 + ((i + st) & 15)) * BK; };
  auto loadW = [&](int kcb, bf16x8 (&aw)[2][2], float4 (&nc)[2]) {
    #pragma unroll
    for (int et = 0; et < 2; ++et) {
      const int ebase = kcb + estripe + et * 16;
      nc[et] = *(const float4*)(ncb + ebase + g * 4);
      const unsigned short* wr = whi + (size_t)(ebase + lm) * DIM + g * 8;
      aw[et][0] = *(const bf16x8*)(wr);
      aw[et][1] = *(const bf16x8*)(wr + 32);
    }
  };
  auto comp = [&](const bf16x8 (&aw)[2][2], const float4 (&nc)[2]) {
    f32x4 acc[2][8];
    #pragma unroll
    for (int et = 0; et < 2; ++et)
      #pragma unroll
      for (int rt = 0; rt < 8; ++rt)
        acc[et][rt] = (f32x4){nc[et].x, nc[et].y, nc[et].z, nc[et].w};
    #pragma unroll
    for (int et = 0; et < 2; ++et)
      #pragma unroll
      for (int s = 0; s < 2; ++s)
        #pragma unroll
        for (int rt = 0; rt < 8; ++rt)
          acc[et][rt] = __builtin_amdgcn_mfma_f32_16x16x32_bf16(
              aw[et][s], bz[rt][s], acc[et][rt], 0, 0, 0);
    #pragma unroll
    for (int rt = 0; rt < 8; ++rt) {
      float cm = fmaxf(
          fmaxf(fmaxf(acc[0][rt][0], acc[0][rt][1]),
                fmaxf(acc[0][rt][2], acc[0][rt][3])),
          fmaxf(fmaxf(acc[1][rt][0], acc[1][rt][1]),
                fmaxf(acc[1][rt][2], acc[1][rt][3])));
      m[rt] = fmaxf(m[rt], cm);
    }
  };

  loadW(chunkbase(0), awA, ncA);
  #pragma unroll 1
  for (int i = 0; i < 16; i += 2) {
    loadW(chunkbase(i + 1), awB, ncB);
    comp(awA, ncA);
    if (i + 2 < 16) loadW(chunkbase(i + 2), awA, ncA);
    comp(awB, ncB);
  }

  #pragma unroll
  for (int rt = 0; rt < 8; ++rt) {
    m[rt] = fmaxf(m[rt], __shfl_xor(m[rt], 16));
    m[rt] = fmaxf(m[rt], __shfl_xor(m[rt], 32));
  }
  if (ln < 16) {
    #pragma unroll
    for (int rt = 0; rt < 8; ++rt)
      atomicMax(&rmx[n0 + rt * 16 + ln], __float_as_uint(m[rt]));
  }
}

// Phase 2: identical sweep (bit-identical scores), collect entries with
// score >= rowmax - EPS into global per-row lists (rare branch per rt).
__global__ __launch_bounds__(256, 2) void collect_kernel(
    const float* __restrict__ z, const unsigned short* __restrict__ whi,
    const float* __restrict__ ncb, const unsigned int* __restrict__ rmx,
    int* __restrict__ cnt, int* __restrict__ cand) {
  const int tid = threadIdx.x;
  const int n0  = (blockIdx.x >> 1) * BMR;
  const int khalf = blockIdx.x & 1;
  const int st  = blockIdx.x & 15;
  const int wv  = tid >> 6;
  const int ln  = tid & 63;
  const int g   = ln >> 4;
  const int lm  = ln & 15;
  const int estripe = wv * 32;

  bf16x8 bz[8][2];
  #pragma unroll
  for (int rt = 0; rt < 8; ++rt) {
    const float* zr = z + (size_t)(n0 + rt * 16 + lm) * DIM;
    #pragma unroll
    for (int s = 0; s < 2; ++s) {
      float4 f0 = *(const float4*)(zr + s * 32 + g * 8);
      float4 f1 = *(const float4*)(zr + s * 32 + g * 8 + 4);
      float ff[8] = {f0.x, f0.y, f0.z, f0.w, f1.x, f1.y, f1.z, f1.w};
      bf16x8 h;
      #pragma unroll
      for (int i = 0; i < 8; ++i) h[i] = (short)f2bf(ff[i]);
      bz[rt][s] = h;
    }
  }

  float thr[8];
  #pragma unroll
  for (int rt = 0; rt < 8; ++rt)
    thr[rt] = __uint_as_float(rmx[n0 + rt * 16 + lm]) - EPS;

  bf16x8 awA[2][2], awB[2][2];
  float4 ncA[2], ncB[2];

  auto chunkbase = [&](int i) { return (khalf * 16 + ((i + st) & 15)) * BK; };
  auto loadW = [&](int kcb, bf16x8 (&aw)[2][2], float4 (&nc)[2]) {
    #pragma unroll
    for (int et = 0; et < 2; ++et) {
      const int ebase = kcb + estripe + et * 16;
      nc[et] = *(const float4*)(ncb + ebase + g * 4);
      const unsigned short* wr = whi + (size_t)(ebase + lm) * DIM + g * 8;
      aw[et][0] = *(const bf16x8*)(wr);
      aw[et][1] = *(const bf16x8*)(wr + 32);
    }
  };
  auto comp = [&](int kcb, const bf16x8 (&aw)[2][2], const float4 (&nc)[2]) {
    f32x4 acc[2][8];
    #pragma unroll
    for (int et = 0; et < 2; ++et)
      #pragma unroll
      for (int rt = 0; rt < 8; ++rt)
        acc[et][rt] = (f32x4){nc[et].x, nc[et].y, nc[et].z, nc[et].w};
    #pragma unroll
    for (int et = 0; et < 2; ++et)
      #pragma unroll
      for (int s = 0; s < 2; ++s)
        #pragma unroll
        for (int rt = 0; rt < 8; ++rt)
          acc[et][rt] = __builtin_amdgcn_mfma_f32_16x16x32_bf16(
              aw[et][s], bz[rt][s], acc[et][rt], 0, 0, 0);
    #pragma unroll
    for (int rt = 0; rt < 8; ++rt) {
      float hm = fmaxf(
          fmaxf(fmaxf(acc[0][rt][0], acc[0][rt][1]),
                fmaxf(acc[0][rt][2], acc[0][rt][3])),
          fmaxf(fmaxf(acc[1][rt][0], acc[1][rt][1]),
                fmaxf(acc[1][rt][2], acc[1][rt][3])));
      if (__builtin_expect(hm >= thr[rt], 0)) {   // rare
        const int rown = n0 + rt * 16 + lm;
        #pragma unroll
        for (int et = 0; et < 2; ++et)
          #pragma unroll
          for (int j = 0; j < 4; ++j) {
            if (acc[et][rt][j] >= thr[rt]) {
              int e = kcb + estripe + et * 16 + g * 4 + j;
              int p = atomicAdd(&cnt[rown], 1);
              if (p < CAPG) cand[rown * CAPG + p] = e;
            }
          }
      }
    }
  };

  loadW(chunkbase(0), awA, ncA);
  #pragma unroll 1
  for (int i = 0; i < 16; i += 2) {
    loadW(chunkbase(i + 1), awB, ncB);
    comp(chunkbase(i), awA, ncA);
    if (i + 2 < 16) loadW(chunkbase(i + 2), awA, ncA);
    comp(chunkbase(i + 1), awB, ncB);
  }
}

// Exact fp64 rescore (lane-per-candidate) + gather/loss/scatter.
__global__ __launch_bounds__(512) void rescore_gather_kernel(
    const float* __restrict__ z, const float* __restrict__ w,
    const int* __restrict__ cnt, const int* __restrict__ cand,
    float* __restrict__ out_idx, float* __restrict__ out_zq,
    float* __restrict__ out_loss, float* __restrict__ enc,
    float* __restrict__ emb) {
  const int bs = blockIdx.x;
  const int tid = threadIdx.x;
  const int h = tid >> 6, d = tid & 63;
  const int n = bs * 8 + h;

  int nn = cnt[n];
  double bl = -1.0e300;
  int wl = 0x7fffffff;
  if (nn <= CAPG) {
    if (d < nn) {                       // lane d rescores candidate d
      int c = cand[n * CAPG + d];
      double td = 0.0, ud = 0.0;
      #pragma unroll 8
      for (int d2 = 0; d2 < DIM; ++d2) {
        double wv = (double)w[(size_t)c * DIM + d2];
        double zv = (double)z[(size_t)n * DIM + d2];
        td = fma(zv, wv, td);
        ud = fma(wv, wv, ud);
      }
      bl = 2.0 * td - ud;
      wl = c;
    }
  } else {                              // overflow: full exact scan (P~0)
    for (int t = 0; t < 64; ++t) {
      int c = t * 64 + d;
      double td = 0.0, ud = 0.0;
      for (int d2 = 0; d2 < DIM; ++d2) {
        double wv = (double)w[(size_t)c * DIM + d2];
        double zv = (double)z[(size_t)n * DIM + d2];
        td = fma(zv, wv, td);
        ud = fma(wv, wv, ud);
      }
      double sd = 2.0 * td - ud;
      if (sd > bl || (sd == bl && c < wl)) { bl = sd; wl = c; }
    }
  }
  #pragma unroll
  for (int mk = 1; mk <= 32; mk <<= 1) {
    double os = __shfl_xor(bl, mk);
    int   oi = __shfl_xor(wl, mk);
    if (os > bl || (os == bl && oi < wl)) { bl = os; wl = oi; }
  }
  int k = wl;
  k = (k < 0) ? 0 : ((k > K_ENT - 1) ? (K_ENT - 1) : k);  // safety clamp
  if (d == 0) out_idx[n] = (float)k;

  const float zf = z[(size_t)n * DIM + d];
  float wvf = w[(size_t)k * DIM + d];
  float stv = zf + (wvf - zf);              // straight-through, ref fp order
  out_zq[(size_t)n * DIM + d] = stv;
  float diff = zf - wvf;
  float s = diff * diff;
  #pragma unroll
  for (int mm = 32; mm >= 1; mm >>= 1) s += __shfl_down(s, mm, 64);
  __shared__ float red[8];
  if ((tid & 63) == 0) red[tid >> 6] = s;
  __syncthreads();
  if (tid == 0) {
    float t = 0.f;
    #pragma unroll
    for (int i = 0; i < 8; ++i) t += red[i];
    out_loss[bs] = t * (1.0f / 512.0f);
  }
  atomicAdd(&emb[(size_t)k * DIM + d], zf);
  if (d == 0) atomicAdd(&enc[k], 1.0f);
}

extern "C" void kernel_launch(void* const* d_in, const int* in_sizes, int n_in,
                              void* d_out, int out_size, void* d_ws, size_t ws_size,
                              hipStream_t stream) {
  const float* z = (const float*)d_in[0];
  const float* w = (const float*)d_in[1];
  float* ws  = (float*)d_ws;
  float* ncb = ws + WS_NCB;
  unsigned short* whi = (unsigned short*)(ws + WS_WHI);
  unsigned int* rmx = (unsigned int*)(ws + WS_RMX);
  int* cnt  = (int*)(ws + WS_CNT);
  int* cand = (int*)(ws + WS_CAND);
  float* out = (float*)d_out;

  hipMemsetAsync(out + OUT_ENC, 0, (size_t)(4096 + 262144) * sizeof(float),
                 stream);
  hipMemsetAsync(rmx, 0, (size_t)(2 * N_TOTAL) * sizeof(int), stream);

  prep_kernel<<<(K_ENT * DIM / 4) / 256, 256, 0, stream>>>(w, whi, ncb);
  maxes_kernel<<<(N_TOTAL / BMR) * 2, 256, 0, stream>>>(z, whi, ncb, rmx);
  collect_kernel<<<(N_TOTAL / BMR) * 2, 256, 0, stream>>>(z, whi, ncb, rmx,
                                                          cnt, cand);
  rescore_gather_kernel<<<N_TOTAL / 8, 512, 0, stream>>>(
      z, w, cnt, cand, out + OUT_IDX, out + OUT_ZQ, out + OUT_LOSS,
      out + OUT_ENC, out + OUT_EMB);
}